// Round 8
// baseline (291.028 us; speedup 1.0000x reference)
//
#include <hip/hip_runtime.h>
#include <hip/hip_bf16.h>

#define Bb 4
#define Cc 96
#define Hh 256
#define Ww 512
#define OC 192
#define HO 128
#define WO 256
#define Gg 16
#define CPG 6

typedef __attribute__((ext_vector_type(4))) float f32x4;
typedef __attribute__((ext_vector_type(8))) short bf16x8;
typedef __attribute__((ext_vector_type(4))) short bf16x4;

static __device__ __forceinline__ ushort f2b(float f) {
    __hip_bfloat16 h = __float2bfloat16(f);
    return *reinterpret_cast<ushort*>(&h);
}
static __device__ __forceinline__ float b2f(ushort u) {
    unsigned int v = ((unsigned int)u) << 16;
    return __builtin_bit_cast(float, v);
}

// ---------------------------------------------------------------------------
// Pack w1, MFMA fragment order, klocal = q*8 + j (verified R7).
// ---------------------------------------------------------------------------
__global__ __launch_bounds__(64) void pack_w1(const float* __restrict__ w1,
                                              ushort* __restrict__ apack) {
    const int blk = blockIdx.x;      // 27*12
    const int k0 = blk / 12;
    const int mf = blk % 12;
    const int lane = threadIdx.x;
    const int m = mf * 16 + (lane & 15);
    const int chunk = k0 / 9;
    const int tap = k0 % 9;
    ushort* dst = apack + (((size_t)(k0 * 12 + mf) * 64) + lane) * 8;
#pragma unroll
    for (int j = 0; j < 8; ++j) {
        const int klocal = ((lane >> 4) << 3) + j;
        const int ic = chunk * 32 + klocal;
        dst[j] = f2b(w1[(size_t)(m * Cc + ic) * 9 + tap]);
    }
}

// ---------------------------------------------------------------------------
// Pack w2, softmax-group row permutation (verified R5) + klocal = q*8+j (R7).
// ---------------------------------------------------------------------------
__global__ __launch_bounds__(64) void pack_w2(const float* __restrict__ w2,
                                              ushort* __restrict__ w2p) {
    const int blk = blockIdx.x;      // 6*9
    const int ks = blk / 9;
    const int mf = blk % 9;
    const int lane = threadIdx.x;
    const int X = lane & 15;
    const int qq = X >> 2;
    const int rr = X & 3;
    const int s = mf * 4 + rr;
    const int g = qq * 4 + s / 9;
    const int k = s % 9;
    const int m = g * 9 + k;
    ushort* dst = w2p + (((size_t)(ks * 9 + mf) * 64) + lane) * 8;
#pragma unroll
    for (int j = 0; j < 8; ++j) {
        const int klocal = ((lane >> 4) << 3) + j;
        const int c = ks * 32 + klocal;
        dst[j] = f2b(w2[(size_t)m * OC + c]);
    }
}

// ---------------------------------------------------------------------------
// Fused kernel. Octet-major LDS layouts (all b128 accesses bank-balanced,
// zero padding):
//   xl: [rp6][oct4][col128][8 ush] = 49152 B    (rp = row*2+par)
//   yl: [coct24][ow128][8 ush]     = 49152 B    (coct = c>>3)
//   p : [144][128] bf16 rotated    = 36864 B
// Union + halo = 49344 B; +sc/bi => ~51 KB => 3 blocks/CU.
// ---------------------------------------------------------------------------
#define XL_MAIN (6 * 4 * 128 * 8)         // 24576 ushorts
#define UNION_USHORTS (XL_MAIN + 3 * 32)  // 24672 ushorts = 49344 B

__global__ __launch_bounds__(256, 3) void fused(
        const float* __restrict__ x, const ushort* __restrict__ apack,
        const ushort* __restrict__ w2p,
        const float* __restrict__ gamma, const float* __restrict__ beta,
        float* __restrict__ out) {
    __shared__ __align__(16) ushort smem[UNION_USHORTS];
    __shared__ float sc[OC], bi[OC];

    const int bid = blockIdx.x;
    const int owt = bid & 1;
    const int oh = (bid >> 1) & 127;
    const int b = bid >> 8;
    const int ow0 = owt * 128;
    const int tid = threadIdx.x;
    const int wid = tid >> 6;
    const int wm = wid & 1;
    const int wn = wid >> 1;
    const int lane = tid & 63;
    const int r = lane & 15;
    const int q = lane >> 4;

    if (tid < OC) {
        const float bnr = 1.0f / sqrtf(1.0f + 1e-5f);
        sc[tid] = gamma[tid] * bnr;
        bi[tid] = beta[tid];
    }

    f32x4 cacc[6][4];
#pragma unroll
    for (int mf = 0; mf < 6; ++mf)
#pragma unroll
        for (int nf = 0; nf < 4; ++nf) cacc[mf][nf] = (f32x4){0.f, 0.f, 0.f, 0.f};

    const size_t chs = (size_t)Hh * Ww;

    // ================= conv phase =================
    for (int chunk = 0; chunk < 3; ++chunk) {
        __syncthreads();
        const int icc = chunk * 32;
#pragma unroll
        for (int it = 0; it < 6; ++it) {
            const int g2 = tid + (it << 8);
            const int oct = g2 & 3;
            const int colp = (g2 >> 2) & 127;
            const int row = g2 >> 9;
            const int ih = 2 * oh - 1 + row;
            const int gcol = 2 * ow0 + 2 * colp;
            float2 v[8];
            if (ih >= 0) {
                const float* xp = x + ((size_t)(b * Cc + icc + (oct << 3)) * Hh + ih) * Ww + gcol;
#pragma unroll
                for (int j = 0; j < 8; ++j)
                    v[j] = *reinterpret_cast<const float2*>(xp + (size_t)j * chs);
            } else {
#pragma unroll
                for (int j = 0; j < 8; ++j) v[j] = make_float2(0.f, 0.f);
            }
            bf16x8 u0, u1;
#pragma unroll
            for (int j = 0; j < 8; ++j) {
                u0[j] = (short)f2b(v[j].x);
                u1[j] = (short)f2b(v[j].y);
            }
            // octet-major: [rp][oct][col][8]
            *reinterpret_cast<bf16x8*>(smem + (((row * 2 + 0) * 4 + oct) * 128 + colp) * 8) = u0;
            *reinterpret_cast<bf16x8*>(smem + (((row * 2 + 1) * 4 + oct) * 128 + colp) * 8) = u1;
        }
        if (tid < 12) {
            const int oct = tid & 3;
            const int row = tid >> 2;
            const int ih = 2 * oh - 1 + row;
            const int gcol = 2 * ow0 - 1;
            float v[8];
            if (ih >= 0 && gcol >= 0) {
                const float* xp = x + ((size_t)(b * Cc + icc + (oct << 3)) * Hh + ih) * Ww + gcol;
#pragma unroll
                for (int j = 0; j < 8; ++j) v[j] = xp[(size_t)j * chs];
            } else {
#pragma unroll
                for (int j = 0; j < 8; ++j) v[j] = 0.f;
            }
            bf16x8 u;
#pragma unroll
            for (int j = 0; j < 8; ++j) u[j] = (short)f2b(v[j]);
            *reinterpret_cast<bf16x8*>(smem + XL_MAIN + row * 32 + oct * 8) = u;
        }
        __syncthreads();

#pragma unroll
        for (int tap = 0; tap < 9; ++tap) {
            const int kh = tap / 3, kw = tap % 3;
            const int par = (kw == 1) ? 0 : 1;
            const int cb = (kw == 0) ? -1 : 0;
            const int k0 = chunk * 9 + tap;

            bf16x8 af[6];
            const ushort* ap = apack + (((size_t)(k0 * 12 + wm * 6) * 64) + lane) * 8;
#pragma unroll
            for (int mf = 0; mf < 6; ++mf)
                af[mf] = *reinterpret_cast<const bf16x8*>(ap + (size_t)mf * 64 * 8);

            bf16x8 bfr[4];
#pragma unroll
            for (int nf = 0; nf < 4; ++nf) {
                const int n = wn * 64 + nf * 16 + r;
                const int colc = n + cb;
                const ushort* src = (colc >= 0)
                    ? smem + (((kh * 2 + par) * 4 + q) * 128 + colc) * 8
                    : smem + XL_MAIN + kh * 32 + q * 8;
                bfr[nf] = *reinterpret_cast<const bf16x8*>(src);
            }
#pragma unroll
            for (int mf = 0; mf < 6; ++mf)
#pragma unroll
                for (int nf = 0; nf < 4; ++nf)
                    cacc[mf][nf] = __builtin_amdgcn_mfma_f32_16x16x32_bf16(
                        af[mf], bfr[nf], cacc[mf][nf], 0, 0, 0);
        }
    }

    // ====== epilogue: BN+LReLU -> yl[coct][ow][8] bf16 ======
    __syncthreads();
#pragma unroll
    for (int mf = 0; mf < 6; ++mf) {
        const int cbase = wm * 96 + mf * 16;
        const int coct = (cbase >> 3) + (q >> 1);
#pragma unroll
        for (int nf = 0; nf < 4; ++nf) {
            const int ow = wn * 64 + nf * 16 + r;
            ushort pk[4];
#pragma unroll
            for (int rr = 0; rr < 4; ++rr) {
                const int oc = cbase + q * 4 + rr;
                float v = cacc[mf][nf][rr] * sc[oc] + bi[oc];
                v = (v >= 0.f) ? v : 0.1f * v;
                pk[rr] = f2b(v);
            }
            *reinterpret_cast<bf16x4*>(smem + (coct * 128 + ow) * 8 + (q & 1) * 4) =
                *reinterpret_cast<bf16x4*>(pk);
        }
    }
    __syncthreads();

    // ============ logits MFMA (permuted w2, b128 B-frags) ============
    f32x4 macc[9][2];
#pragma unroll
    for (int mf = 0; mf < 9; ++mf)
#pragma unroll
        for (int nf = 0; nf < 2; ++nf) macc[mf][nf] = (f32x4){0.f, 0.f, 0.f, 0.f};

#pragma unroll
    for (int ks = 0; ks < 6; ++ks) {
        bf16x8 af[9];
        const ushort* ap = w2p + (((size_t)(ks * 9) * 64) + lane) * 8;
#pragma unroll
        for (int mf = 0; mf < 9; ++mf)
            af[mf] = *reinterpret_cast<const bf16x8*>(ap + (size_t)mf * 64 * 8);
        bf16x8 bfr[2];
#pragma unroll
        for (int nf = 0; nf < 2; ++nf) {
            const int ow = wid * 32 + nf * 16 + r;
            bfr[nf] = *reinterpret_cast<const bf16x8*>(smem + ((ks * 4 + q) * 128 + ow) * 8);
        }
#pragma unroll
        for (int mf = 0; mf < 9; ++mf)
#pragma unroll
            for (int nf = 0; nf < 2; ++nf)
                macc[mf][nf] = __builtin_amdgcn_mfma_f32_16x16x32_bf16(
                    af[mf], bfr[nf], macc[mf][nf], 0, 0, 0);
    }
    __syncthreads();   // yl reads done; p overwrites

    // ===== in-register softmax -> p to LDS (bf16, normalized, rotated) =====
#pragma unroll
    for (int nf = 0; nf < 2; ++nf) {
        const int ow = wid * 32 + nf * 16 + r;
#pragma unroll
        for (int gl = 0; gl < 4; ++gl) {
            const int g = q * 4 + gl;
            float pv[9];
            float mx = -1e30f;
#pragma unroll
            for (int k = 0; k < 9; ++k) {
                const int s = gl * 9 + k;
                pv[k] = macc[s >> 2][nf][s & 3];
                mx = fmaxf(mx, pv[k]);
            }
            float ssum = 0.f;
#pragma unroll
            for (int k = 0; k < 9; ++k) { pv[k] = __expf(pv[k] - mx); ssum += pv[k]; }
            const float inv = 1.f / ssum;
            const int col = (ow + q * 16) & 127;
#pragma unroll
            for (int k = 0; k < 9; ++k)
                smem[(g * 9 + k) * 128 + col] = f2b(pv[k] * inv);
        }
    }
    __syncthreads();

    // ============ apply phase (coalesced) ============
    const int ih0 = 2 * oh - 1;
    const bool okh0 = (oh > 0);
#pragma unroll
    for (int it = 0; it < 8; ++it) {
        const int idx = (it << 8) + tid;
        const int g = idx >> 7;
        const int owl = idx & 127;
        const int owg = ow0 + owl;
        const int rot = (g >> 2) * 16;
        const int col = (owl + rot) & 127;

        float p[9];
#pragma unroll
        for (int k = 0; k < 9; ++k) p[k] = b2f(smem[(g * 9 + k) * 128 + col]);

        const int iw0 = 2 * owg - 1;
        const bool okw0 = (owg > 0);
#pragma unroll
        for (int i = 0; i < CPG; ++i) {
            const int cc = i * Gg + g;
            const float* xc = x + (size_t)(b * Cc + cc) * chs;
            float acc = 0.f;
#pragma unroll
            for (int kh = 0; kh < 3; ++kh) {
                if (kh == 0 && !okh0) continue;
                const float* rowp = xc + (size_t)(ih0 + kh) * Ww + iw0;
                const float v0 = okw0 ? rowp[0] : 0.f;
                const float2 v12 = *reinterpret_cast<const float2*>(rowp + 1);
                acc += p[kh * 3 + 0] * v0 + p[kh * 3 + 1] * v12.x
                     + p[kh * 3 + 2] * v12.y;
            }
            out[((size_t)(b * Cc + cc) * HO + oh) * WO + owg] = acc;
        }
    }
}

extern "C" void kernel_launch(void* const* d_in, const int* in_sizes, int n_in,
                              void* d_out, int out_size, void* d_ws, size_t ws_size,
                              hipStream_t stream) {
    const float* x     = (const float*)d_in[0];
    const float* w1    = (const float*)d_in[1];
    const float* gamma = (const float*)d_in[2];
    const float* beta  = (const float*)d_in[3];
    const float* w2    = (const float*)d_in[4];
    float* out = (float*)d_out;

    ushort* apack = (ushort*)d_ws;                           // 331,776 B
    ushort* w2p   = (ushort*)((char*)d_ws + 331776);         // + 55,296 B

    pack_w1<<<27 * 12, 64, 0, stream>>>(w1, apack);
    pack_w2<<<6 * 9, 64, 0, stream>>>(w2, w2p);
    fused<<<Bb * HO * 2, 256, 0, stream>>>(x, apack, w2p, gamma, beta, out);
}

// Round 9
// 189.281 us; speedup vs baseline: 1.5375x; 1.5375x over previous
//
#include <hip/hip_runtime.h>
#include <hip/hip_bf16.h>

#define Bb 4
#define Cc 96
#define Hh 256
#define Ww 512
#define OC 192
#define HO 128
#define WO 256
#define Gg 16
#define CPG 6

typedef __attribute__((ext_vector_type(4))) float f32x4;
typedef __attribute__((ext_vector_type(8))) short bf16x8;
typedef __attribute__((ext_vector_type(4))) short bf16x4;

static __device__ __forceinline__ ushort f2b(float f) {
    __hip_bfloat16 h = __float2bfloat16(f);
    return *reinterpret_cast<ushort*>(&h);
}
static __device__ __forceinline__ float b2f(ushort u) {
    unsigned int v = ((unsigned int)u) << 16;
    return __builtin_bit_cast(float, v);
}

// ---------------------------------------------------------------------------
// Pack w1, MFMA fragment order, klocal = q*8 + j (verified R7).
// ---------------------------------------------------------------------------
__global__ __launch_bounds__(64) void pack_w1(const float* __restrict__ w1,
                                              ushort* __restrict__ apack) {
    const int blk = blockIdx.x;      // 27*12
    const int k0 = blk / 12;
    const int mf = blk % 12;
    const int lane = threadIdx.x;
    const int m = mf * 16 + (lane & 15);
    const int chunk = k0 / 9;
    const int tap = k0 % 9;
    ushort* dst = apack + (((size_t)(k0 * 12 + mf) * 64) + lane) * 8;
#pragma unroll
    for (int j = 0; j < 8; ++j) {
        const int klocal = ((lane >> 4) << 3) + j;
        const int ic = chunk * 32 + klocal;
        dst[j] = f2b(w1[(size_t)(m * Cc + ic) * 9 + tap]);
    }
}

// ---------------------------------------------------------------------------
// Pack w2, softmax-group row permutation (verified R5) + klocal = q*8+j (R7).
// ---------------------------------------------------------------------------
__global__ __launch_bounds__(64) void pack_w2(const float* __restrict__ w2,
                                              ushort* __restrict__ w2p) {
    const int blk = blockIdx.x;      // 6*9
    const int ks = blk / 9;
    const int mf = blk % 9;
    const int lane = threadIdx.x;
    const int X = lane & 15;
    const int qq = X >> 2;
    const int rr = X & 3;
    const int s = mf * 4 + rr;
    const int g = qq * 4 + s / 9;
    const int k = s % 9;
    const int m = g * 9 + k;
    ushort* dst = w2p + (((size_t)(ks * 9 + mf) * 64) + lane) * 8;
#pragma unroll
    for (int j = 0; j < 8; ++j) {
        const int klocal = ((lane >> 4) << 3) + j;
        const int c = ks * 32 + klocal;
        dst[j] = f2b(w2[(size_t)m * OC + c]);
    }
}

// ---------------------------------------------------------------------------
// Fused kernel, 512 threads (8 waves) per block for 4 waves/SIMD residency.
// Conv wave tile M=96 x N=32 (wm=wid&1, wn=wid>>1); logits wave tile
// M=144 x N=16 (ow = wid*16+r). Octet-major LDS (R8 layout, R7 bounds logic):
//   xl: [rp6][oct4][col128][8 ush] = 49152 B
//   yl: [coct24][ow128][8 ush]     = 49152 B
//   p : [144][128] bf16 rotated    = 36864 B
// ---------------------------------------------------------------------------
#define XL_MAIN (6 * 4 * 128 * 8)         // 24576 ushorts
#define UNION_USHORTS (XL_MAIN + 3 * 32)  // 24672 ushorts = 49344 B

__global__ __launch_bounds__(512, 4) void fused(
        const float* __restrict__ x, const ushort* __restrict__ apack,
        const ushort* __restrict__ w2p,
        const float* __restrict__ gamma, const float* __restrict__ beta,
        float* __restrict__ out) {
    __shared__ __align__(16) ushort smem[UNION_USHORTS];
    __shared__ float sc[OC], bi[OC];

    const int bid = blockIdx.x;
    const int owt = bid & 1;
    const int oh = (bid >> 1) & 127;
    const int b = bid >> 8;
    const int ow0 = owt * 128;
    const int tid = threadIdx.x;
    const int wid = tid >> 6;       // 0..7
    const int wm = wid & 1;         // conv M half: oc base wm*96
    const int wn = wid >> 1;        // conv N quarter: ow base wn*32
    const int lane = tid & 63;
    const int r = lane & 15;
    const int q = lane >> 4;

    if (tid < OC) {
        const float bnr = 1.0f / sqrtf(1.0f + 1e-5f);
        sc[tid] = gamma[tid] * bnr;
        bi[tid] = beta[tid];
    }

    f32x4 cacc[6][2];
#pragma unroll
    for (int mf = 0; mf < 6; ++mf)
#pragma unroll
        for (int nf = 0; nf < 2; ++nf) cacc[mf][nf] = (f32x4){0.f, 0.f, 0.f, 0.f};

    const size_t chs = (size_t)Hh * Ww;

    // ================= conv phase =================
    for (int chunk = 0; chunk < 3; ++chunk) {
        __syncthreads();
        const int icc = chunk * 32;
#pragma unroll
        for (int it = 0; it < 3; ++it) {
            const int g2 = tid + (it << 9);
            const int oct = g2 & 3;
            const int colp = (g2 >> 2) & 127;
            const int row = g2 >> 9;
            const int ih = 2 * oh - 1 + row;
            const int gcol = 2 * ow0 + 2 * colp;
            float2 v[8];
            if (ih >= 0) {
                const float* xp = x + ((size_t)(b * Cc + icc + (oct << 3)) * Hh + ih) * Ww + gcol;
#pragma unroll
                for (int j = 0; j < 8; ++j)
                    v[j] = *reinterpret_cast<const float2*>(xp + (size_t)j * chs);
            } else {
#pragma unroll
                for (int j = 0; j < 8; ++j) v[j] = make_float2(0.f, 0.f);
            }
            bf16x8 u0, u1;
#pragma unroll
            for (int j = 0; j < 8; ++j) {
                u0[j] = (short)f2b(v[j].x);
                u1[j] = (short)f2b(v[j].y);
            }
            *reinterpret_cast<bf16x8*>(smem + (((row * 2 + 0) * 4 + oct) * 128 + colp) * 8) = u0;
            *reinterpret_cast<bf16x8*>(smem + (((row * 2 + 1) * 4 + oct) * 128 + colp) * 8) = u1;
        }
        if (tid < 12) {
            const int oct = tid & 3;
            const int row = tid >> 2;
            const int ih = 2 * oh - 1 + row;
            const int gcol = 2 * ow0 - 1;
            float v[8];
            if (ih >= 0 && gcol >= 0) {
                const float* xp = x + ((size_t)(b * Cc + icc + (oct << 3)) * Hh + ih) * Ww + gcol;
#pragma unroll
                for (int j = 0; j < 8; ++j) v[j] = xp[(size_t)j * chs];
            } else {
#pragma unroll
                for (int j = 0; j < 8; ++j) v[j] = 0.f;
            }
            bf16x8 u;
#pragma unroll
            for (int j = 0; j < 8; ++j) u[j] = (short)f2b(v[j]);
            *reinterpret_cast<bf16x8*>(smem + XL_MAIN + row * 32 + oct * 8) = u;
        }
        __syncthreads();

#pragma unroll
        for (int tap = 0; tap < 9; ++tap) {
            const int kh = tap / 3, kw = tap % 3;
            const int par = (kw == 1) ? 0 : 1;
            const int cb = (kw == 0) ? -1 : 0;
            const int k0 = chunk * 9 + tap;

            bf16x8 af[6];
            const ushort* ap = apack + (((size_t)(k0 * 12 + wm * 6) * 64) + lane) * 8;
#pragma unroll
            for (int mf = 0; mf < 6; ++mf)
                af[mf] = *reinterpret_cast<const bf16x8*>(ap + (size_t)mf * 64 * 8);

            bf16x8 bfr[2];
#pragma unroll
            for (int nf = 0; nf < 2; ++nf) {
                const int n = wn * 32 + nf * 16 + r;
                const int colc = n + cb;
                const ushort* src = (colc >= 0)
                    ? smem + (((kh * 2 + par) * 4 + q) * 128 + colc) * 8
                    : smem + XL_MAIN + kh * 32 + q * 8;
                bfr[nf] = *reinterpret_cast<const bf16x8*>(src);
            }
#pragma unroll
            for (int mf = 0; mf < 6; ++mf)
#pragma unroll
                for (int nf = 0; nf < 2; ++nf)
                    cacc[mf][nf] = __builtin_amdgcn_mfma_f32_16x16x32_bf16(
                        af[mf], bfr[nf], cacc[mf][nf], 0, 0, 0);
        }
    }

    // ====== epilogue: BN+LReLU -> yl[coct][ow][8] bf16 ======
    __syncthreads();
#pragma unroll
    for (int mf = 0; mf < 6; ++mf) {
        const int cbase = wm * 96 + mf * 16;
        const int coct = (cbase >> 3) + (q >> 1);
#pragma unroll
        for (int nf = 0; nf < 2; ++nf) {
            const int ow = wn * 32 + nf * 16 + r;
            ushort pk[4];
#pragma unroll
            for (int rr = 0; rr < 4; ++rr) {
                const int oc = cbase + q * 4 + rr;
                float v = cacc[mf][nf][rr] * sc[oc] + bi[oc];
                v = (v >= 0.f) ? v : 0.1f * v;
                pk[rr] = f2b(v);
            }
            *reinterpret_cast<bf16x4*>(smem + (coct * 128 + ow) * 8 + (q & 1) * 4) =
                *reinterpret_cast<bf16x4*>(pk);
        }
    }
    __syncthreads();

    // ============ logits MFMA: wave tile M=144 x N=16 ============
    f32x4 macc[9];
#pragma unroll
    for (int mf = 0; mf < 9; ++mf) macc[mf] = (f32x4){0.f, 0.f, 0.f, 0.f};

    const int owq = wid * 16 + r;   // this lane's logits column
#pragma unroll
    for (int ks = 0; ks < 6; ++ks) {
        bf16x8 af[9];
        const ushort* ap = w2p + (((size_t)(ks * 9) * 64) + lane) * 8;
#pragma unroll
        for (int mf = 0; mf < 9; ++mf)
            af[mf] = *reinterpret_cast<const bf16x8*>(ap + (size_t)mf * 64 * 8);
        bf16x8 bfr = *reinterpret_cast<const bf16x8*>(smem + ((ks * 4 + q) * 128 + owq) * 8);
#pragma unroll
        for (int mf = 0; mf < 9; ++mf)
            macc[mf] = __builtin_amdgcn_mfma_f32_16x16x32_bf16(af[mf], bfr, macc[mf], 0, 0, 0);
    }
    __syncthreads();   // yl reads done; p overwrites

    // ===== in-register softmax -> p to LDS (bf16, normalized, rotated) =====
    {
        const int col = (owq + q * 16) & 127;
#pragma unroll
        for (int gl = 0; gl < 4; ++gl) {
            const int g = q * 4 + gl;
            float pv[9];
            float mx = -1e30f;
#pragma unroll
            for (int k = 0; k < 9; ++k) {
                const int s = gl * 9 + k;
                pv[k] = macc[s >> 2][s & 3];
                mx = fmaxf(mx, pv[k]);
            }
            float ssum = 0.f;
#pragma unroll
            for (int k = 0; k < 9; ++k) { pv[k] = __expf(pv[k] - mx); ssum += pv[k]; }
            const float inv = 1.f / ssum;
#pragma unroll
            for (int k = 0; k < 9; ++k)
                smem[(g * 9 + k) * 128 + col] = f2b(pv[k] * inv);
        }
    }
    __syncthreads();

    // ============ apply phase (coalesced) ============
    const int ih0 = 2 * oh - 1;
    const bool okh0 = (oh > 0);
#pragma unroll
    for (int it = 0; it < 4; ++it) {
        const int idx = (it << 9) + tid;
        const int g = idx >> 7;
        const int owl = idx & 127;
        const int owg = ow0 + owl;
        const int rot = (g >> 2) * 16;
        const int col = (owl + rot) & 127;

        float p[9];
#pragma unroll
        for (int k = 0; k < 9; ++k) p[k] = b2f(smem[(g * 9 + k) * 128 + col]);

        const int iw0 = 2 * owg - 1;
        const bool okw0 = (owg > 0);
#pragma unroll
        for (int i = 0; i < CPG; ++i) {
            const int cc = i * Gg + g;
            const float* xc = x + (size_t)(b * Cc + cc) * chs;
            float acc = 0.f;
#pragma unroll
            for (int kh = 0; kh < 3; ++kh) {
                if (kh == 0 && !okh0) continue;
                const float* rowp = xc + (size_t)(ih0 + kh) * Ww + iw0;
                const float v0 = okw0 ? rowp[0] : 0.f;
                const float2 v12 = *reinterpret_cast<const float2*>(rowp + 1);
                acc += p[kh * 3 + 0] * v0 + p[kh * 3 + 1] * v12.x
                     + p[kh * 3 + 2] * v12.y;
            }
            out[((size_t)(b * Cc + cc) * HO + oh) * WO + owg] = acc;
        }
    }
}

extern "C" void kernel_launch(void* const* d_in, const int* in_sizes, int n_in,
                              void* d_out, int out_size, void* d_ws, size_t ws_size,
                              hipStream_t stream) {
    const float* x     = (const float*)d_in[0];
    const float* w1    = (const float*)d_in[1];
    const float* gamma = (const float*)d_in[2];
    const float* beta  = (const float*)d_in[3];
    const float* w2    = (const float*)d_in[4];
    float* out = (float*)d_out;

    ushort* apack = (ushort*)d_ws;                           // 331,776 B
    ushort* w2p   = (ushort*)((char*)d_ws + 331776);         // + 55,296 B

    pack_w1<<<27 * 12, 64, 0, stream>>>(w1, apack);
    pack_w2<<<6 * 9, 64, 0, stream>>>(w2, w2p);
    fused<<<Bb * HO * 2, 512, 0, stream>>>(x, apack, w2p, gamma, beta, out);
}